// Round 1
// baseline (262.417 us; speedup 1.0000x reference)
//
#include <hip/hip_runtime.h>
#include <stdint.h>

#define FILTER_TH 1.5f
#define CAP 2048
#define DELTA_W 0.2f

// Monotone map: float -> uint32 preserving order (x1 < x2 <=> u(x1) < u(x2))
__device__ __forceinline__ unsigned f2u(float x) {
    unsigned b = __float_as_uint(x);
    return (b & 0x80000000u) ? ~b : (b | 0x80000000u);
}
__device__ __forceinline__ float u2f(unsigned u) {
    unsigned b = (u & 0x80000000u) ? (u & 0x7fffffffu) : ~u;
    return __uint_as_float(b);
}

__global__ __launch_bounds__(256) void dtl_rows(const float* __restrict__ in,
                                                const int* __restrict__ targets,
                                                float* __restrict__ ws,
                                                int N, int K) {
    __shared__ unsigned cand[CAP];
    __shared__ int s_cnt;

    const int row = blockIdx.x;
    const size_t rowoff = (size_t)row * (size_t)N;
    const float* __restrict__ p = in + rowoff;
    const int tgt = targets[row];
    const int tid = threadIdx.x;
    const int lane = tid & 63;

    if (tid == 0) s_cnt = 0;
    __syncthreads();

    // ---- Pass 1: filter x > FILTER_TH (excluding target col) into LDS ----
    // Alignment: rows have odd stride; scalar head/tail, float4 body.
    int a0 = (int)((4 - (rowoff & 3)) & 3);
    if (a0 > N) a0 = N;
    const int nv = (N - a0) >> 2;
    const int tail0 = a0 + nv * 4;

    if (tid < a0) {
        float x = p[tid];
        if (x > FILTER_TH && tid != tgt) {
            int b = atomicAdd(&s_cnt, 1);
            if (b < CAP) cand[b] = f2u(x);
        }
    }
    {
        int c = tail0 + tid;
        if (c < N) {
            float x = p[c];
            if (x > FILTER_TH && c != tgt) {
                int b = atomicAdd(&s_cnt, 1);
                if (b < CAP) cand[b] = f2u(x);
            }
        }
    }

    const float4* __restrict__ pv = (const float4*)(p + a0);
    const int nIter = (nv + 255) >> 8;
    for (int it = 0; it < nIter; ++it) {  // uniform trip count -> ballots safe
        int i = it * 256 + tid;
        bool inb = i < nv;
        float4 v = make_float4(-1e30f, -1e30f, -1e30f, -1e30f);
        if (inb) v = pv[i];
        int c0 = a0 + i * 4;
        float xs[4] = {v.x, v.y, v.z, v.w};
#pragma unroll
        for (int j = 0; j < 4; ++j) {
            bool pred = inb && (xs[j] > FILTER_TH) && (c0 + j != tgt);
            unsigned long long m = __ballot(pred);
            int total = __popcll(m);
            int base = 0;
            if (lane == 0 && total) base = atomicAdd(&s_cnt, total);
            base = __shfl(base, 0);
            if (pred) {
                int idx = base + __popcll(m & ((1ull << lane) - 1));
                if (idx < CAP) cand[idx] = f2u(xs[j]);
            }
        }
    }
    __syncthreads();
    const int nC = s_cnt;

    // ---- Pass 2: wave 0 finds K-th largest and the tie-corrected sum ----
    if (tid < 64) {
        const bool fast = (nC >= K && nC <= CAP);
        unsigned thr = 0;
        if (fast) {
            // bit-greedy: max v with count(u >= v) >= K  ==  K-th largest u
            for (int bit = 31; bit >= 0; --bit) {
                unsigned trial = thr | (1u << bit);
                int cnt = 0;
                for (int i = lane; i < nC; i += 64) cnt += (cand[i] >= trial);
                for (int off = 32; off > 0; off >>= 1) cnt += __shfl_down(cnt, off);
                cnt = __shfl(cnt, 0);
                if (cnt >= K) thr = trial;
            }
            int gt = 0;
            float s = 0.f;
            for (int i = lane; i < nC; i += 64) {
                unsigned u = cand[i];
                if (u > thr) {
                    gt++;
                    float e = 1.f + u2f(u);
                    s += e * e;
                }
            }
            for (int off = 32; off > 0; off >>= 1) {
                gt += __shfl_down(gt, off);
                s += __shfl_down(s, off);
            }
            if (lane == 0) {
                float et = 1.f + u2f(thr);
                float sum = s + (float)(K - gt) * et * et;
                float d = 1.f - p[tgt];
                ws[row] = d * d + DELTA_W * sum / (float)K;
            }
        } else {
            // Slow exact fallback over global row (never hit for N(0,1) data)
            for (int bit = 31; bit >= 0; --bit) {
                unsigned trial = thr | (1u << bit);
                int cnt = 0;
                for (int i = lane; i < N; i += 64) {
                    if (i == tgt) continue;
                    cnt += (f2u(p[i]) >= trial);
                }
                for (int off = 32; off > 0; off >>= 1) cnt += __shfl_down(cnt, off);
                cnt = __shfl(cnt, 0);
                if (cnt >= K) thr = trial;
            }
            int gt = 0;
            float s = 0.f;
            for (int i = lane; i < N; i += 64) {
                if (i == tgt) continue;
                unsigned u = f2u(p[i]);
                if (u > thr) {
                    gt++;
                    float e = 1.f + u2f(u);
                    s += e * e;
                }
            }
            for (int off = 32; off > 0; off >>= 1) {
                gt += __shfl_down(gt, off);
                s += __shfl_down(s, off);
            }
            if (lane == 0) {
                float et = 1.f + u2f(thr);
                float sum = s + (float)(K - gt) * et * et;
                float d = 1.f - p[tgt];
                ws[row] = d * d + DELTA_W * sum / (float)K;
            }
        }
    }
}

__global__ __launch_bounds__(256) void dtl_reduce(const float* __restrict__ ws,
                                                  float* __restrict__ out, int M) {
    __shared__ float sh[4];
    float s = 0.f;
    for (int i = threadIdx.x; i < M; i += 256) s += ws[i];
    for (int off = 32; off > 0; off >>= 1) s += __shfl_down(s, off);
    int wid = threadIdx.x >> 6;
    if ((threadIdx.x & 63) == 0) sh[wid] = s;
    __syncthreads();
    if (threadIdx.x == 0) out[0] = (sh[0] + sh[1] + sh[2] + sh[3]) / (float)M;
}

extern "C" void kernel_launch(void* const* d_in, const int* in_sizes, int n_in,
                              void* d_out, int out_size, void* d_ws, size_t ws_size,
                              hipStream_t stream) {
    const float* in = (const float*)d_in[0];
    const int* tgt = (const int*)d_in[1];
    const int M = in_sizes[1];
    const int N = in_sizes[0] / M;
    int K = (int)(0.01 * (double)(N - 1));  // matches Python int(R*(n-1)) = 100
    if (K < 1) K = 1;

    float* ws = (float*)d_ws;    // M floats of per-row loss
    float* out = (float*)d_out;  // scalar mean

    dtl_rows<<<M, 256, 0, stream>>>(in, tgt, ws, N, K);
    dtl_reduce<<<1, 256, 0, stream>>>(ws, out, M);
}

// Round 2
// 237.817 us; speedup vs baseline: 1.1034x; 1.1034x over previous
//
#include <hip/hip_runtime.h>
#include <stdint.h>

#define FILTER_TH 1.5f
#define CAP 2048
#define NB 256
#define BIN_SCALE 64.0f   // bin width 1/64 over [1.5, 5.5); bin 255 catches x>=5.484
#define BCAP 64
#define DELTA_W 0.2f
#define NITER 10          // 10 * 256 * 4 = 10240 >= 10001 elements per row

// Monotone map float -> uint32 (order-preserving), for exact fallbacks only
__device__ __forceinline__ unsigned f2u(float x) {
    unsigned b = __float_as_uint(x);
    return (b & 0x80000000u) ? ~b : (b | 0x80000000u);
}
__device__ __forceinline__ float u2f(unsigned u) {
    unsigned b = (u & 0x80000000u) ? (u & 0x7fffffffu) : ~u;
    return __uint_as_float(b);
}

__global__ __launch_bounds__(256) void dtl_rows(const float* __restrict__ in,
                                                const int* __restrict__ targets,
                                                float* __restrict__ ws,
                                                int N, int K) {
    __shared__ float cand[CAP];
    __shared__ int s_hist[NB];
    __shared__ float s_bstar[BCAP];
    __shared__ float s_partial[4];
    __shared__ int s_pcnt[4];
    __shared__ int s_cnt, s_bcnt, s_bsel, s_chi;

    const int row = blockIdx.x;
    const size_t rowoff = (size_t)row * (size_t)N;
    const float* __restrict__ p = in + rowoff;
    const int tgt = targets[row];
    const int tid = threadIdx.x;
    const int lane = tid & 63;
    const int wid = tid >> 6;

    if (tid == 0) { s_cnt = 0; s_bcnt = 0; s_bsel = -1; s_chi = 0; }
    if (tid < NB) s_hist[tid] = 0;
    __syncthreads();

    auto push = [&](float x) {
        int b = atomicAdd(&s_cnt, 1);
        if (b < CAP) cand[b] = x;
        int bin = (int)((x - FILTER_TH) * BIN_SCALE);
        if (bin > NB - 1) bin = NB - 1;
        atomicAdd(&s_hist[bin], 1);
    };

    // ---- Pass 1: filter x > FILTER_TH (excluding target col) into LDS ----
    int a0 = (int)((4 - (rowoff & 3)) & 3);
    if (a0 > N) a0 = N;
    const int nv = (N - a0) >> 2;
    const int tail0 = a0 + nv * 4;

    if (tid < a0) {
        float x = p[tid];
        if (x > FILTER_TH && tid != tgt) push(x);
    }
    {
        int c = tail0 + tid;
        if (c < N) {
            float x = p[c];
            if (x > FILTER_TH && c != tgt) push(x);
        }
    }

    const float4* __restrict__ pv = (const float4*)(p + a0);
    for (int base = 0; base < nv; base += NITER * 256) {
        float4 buf[NITER];
#pragma unroll
        for (int it = 0; it < NITER; ++it) {   // all loads issued before any use
            int i = base + it * 256 + tid;
            buf[it] = (i < nv) ? pv[i]
                               : make_float4(-1e30f, -1e30f, -1e30f, -1e30f);
        }
#pragma unroll
        for (int it = 0; it < NITER; ++it) {
            int i = base + it * 256 + tid;
            int c0 = a0 + i * 4;
            float xs[4] = {buf[it].x, buf[it].y, buf[it].z, buf[it].w};
#pragma unroll
            for (int j = 0; j < 4; ++j) {
                float x = xs[j];
                if (x > FILTER_TH && (c0 + j) != tgt) push(x);
            }
        }
    }
    __syncthreads();
    const int nC = s_cnt;
    const bool fast = (nC >= K && nC <= CAP);
    bool hist_done = false;

    if (fast) {
        // ---- find threshold bin b* and count-above c_hi (wave 0) ----
        if (wid == 0) {
            int base4 = lane * 4;
            int h0 = s_hist[base4], h1 = s_hist[base4 + 1];
            int h2 = s_hist[base4 + 2], h3 = s_hist[base4 + 3];
            int cum = h0 + h1 + h2 + h3;
#pragma unroll
            for (int off = 1; off < 64; off <<= 1) {   // reverse inclusive scan
                int v = __shfl_down(cum, off);
                if (lane + off < 64) cum += v;
            }
            int cn = __shfl_down(cum, 1);
            if (lane == 63) cn = 0;
            if (cum >= K && cn < K) {                  // unique crossing lane
                int cacc = cn;
                int hh[4] = {h0, h1, h2, h3};
                for (int t = 3; t >= 0; --t) {
                    cacc += hh[t];
                    if (cacc >= K) {
                        s_bsel = base4 + t;
                        s_chi = cacc - hh[t];
                        break;
                    }
                }
            }
        }
        __syncthreads();
        const int bsel = s_bsel;
        const int chi = s_chi;

        // ---- classify candidates: sum bins > b*, collect bin b* ----
        float lsum = 0.f;
        for (int i = tid; i < nC; i += 256) {
            float x = cand[i];
            int bin = (int)((x - FILTER_TH) * BIN_SCALE);
            if (bin > NB - 1) bin = NB - 1;
            if (bin > bsel) {
                float e = 1.f + x;
                lsum += e * e;
            } else if (bin == bsel) {
                int b = atomicAdd(&s_bcnt, 1);
                if (b < BCAP) s_bstar[b] = x;
            }
        }
        for (int off = 32; off > 0; off >>= 1) lsum += __shfl_down(lsum, off);
        if (lane == 0) s_partial[wid] = lsum;
        __syncthreads();
        const int mB = s_bcnt;
        if (mB <= BCAP) {
            if (tid == 0) {
                float sum = s_partial[0] + s_partial[1] + s_partial[2] + s_partial[3];
                int need = K - chi;                    // >=1, <= mB by construction
                for (int r = 0; r < need; ++r) {       // top-`need` of tiny bin
                    int bi = 0; float bx = -1e30f;
                    for (int i = 0; i < mB; ++i) {
                        float x = s_bstar[i];
                        if (x > bx) { bx = x; bi = i; }
                    }
                    float e = 1.f + bx;
                    sum += e * e;
                    s_bstar[bi] = -1e30f;
                }
                float d = 1.f - p[tgt];
                ws[row] = d * d + DELTA_W * sum / (float)K;
            }
            hist_done = true;
        }
        __syncthreads();
    }

    if (!hist_done && tid < 64) {
        // ---- exact fallbacks (never hit for N(0,1) data) ----
        unsigned thr = 0;
        if (fast) {
            // bit-search over complete LDS candidate list
            for (int bit = 31; bit >= 0; --bit) {
                unsigned trial = thr | (1u << bit);
                int cnt = 0;
                for (int i = lane; i < nC; i += 64) cnt += (f2u(cand[i]) >= trial);
                for (int off = 32; off > 0; off >>= 1) cnt += __shfl_down(cnt, off);
                cnt = __shfl(cnt, 0);
                if (cnt >= K) thr = trial;
            }
            int gt = 0; float s = 0.f;
            for (int i = lane; i < nC; i += 64) {
                unsigned u = f2u(cand[i]);
                if (u > thr) { gt++; float e = 1.f + u2f(u); s += e * e; }
            }
            for (int off = 32; off > 0; off >>= 1) {
                gt += __shfl_down(gt, off); s += __shfl_down(s, off);
            }
            if (lane == 0) {
                float et = 1.f + u2f(thr);
                float sum = s + (float)(K - gt) * et * et;
                float d = 1.f - p[tgt];
                ws[row] = d * d + DELTA_W * sum / (float)K;
            }
        } else {
            // bit-search over full global row
            for (int bit = 31; bit >= 0; --bit) {
                unsigned trial = thr | (1u << bit);
                int cnt = 0;
                for (int i = lane; i < N; i += 64) {
                    if (i == tgt) continue;
                    cnt += (f2u(p[i]) >= trial);
                }
                for (int off = 32; off > 0; off >>= 1) cnt += __shfl_down(cnt, off);
                cnt = __shfl(cnt, 0);
                if (cnt >= K) thr = trial;
            }
            int gt = 0; float s = 0.f;
            for (int i = lane; i < N; i += 64) {
                if (i == tgt) continue;
                unsigned u = f2u(p[i]);
                if (u > thr) { gt++; float e = 1.f + u2f(u); s += e * e; }
            }
            for (int off = 32; off > 0; off >>= 1) {
                gt += __shfl_down(gt, off); s += __shfl_down(s, off);
            }
            if (lane == 0) {
                float et = 1.f + u2f(thr);
                float sum = s + (float)(K - gt) * et * et;
                float d = 1.f - p[tgt];
                ws[row] = d * d + DELTA_W * sum / (float)K;
            }
        }
    }
}

__global__ __launch_bounds__(256) void dtl_reduce(const float* __restrict__ ws,
                                                  float* __restrict__ out, int M) {
    __shared__ float sh[4];
    float s = 0.f;
    for (int i = threadIdx.x; i < M; i += 256) s += ws[i];
    for (int off = 32; off > 0; off >>= 1) s += __shfl_down(s, off);
    int wid = threadIdx.x >> 6;
    if ((threadIdx.x & 63) == 0) sh[wid] = s;
    __syncthreads();
    if (threadIdx.x == 0) out[0] = (sh[0] + sh[1] + sh[2] + sh[3]) / (float)M;
}

extern "C" void kernel_launch(void* const* d_in, const int* in_sizes, int n_in,
                              void* d_out, int out_size, void* d_ws, size_t ws_size,
                              hipStream_t stream) {
    const float* in = (const float*)d_in[0];
    const int* tgt = (const int*)d_in[1];
    const int M = in_sizes[1];
    const int N = in_sizes[0] / M;
    int K = (int)(0.01 * (double)(N - 1));  // matches Python int(R*(n-1)) = 100
    if (K < 1) K = 1;

    float* ws = (float*)d_ws;
    float* out = (float*)d_out;

    dtl_rows<<<M, 256, 0, stream>>>(in, tgt, ws, N, K);
    dtl_reduce<<<1, 256, 0, stream>>>(ws, out, M);
}